// Round 8
// baseline (333.389 us; speedup 1.0000x reference)
//
#include <hip/hip_runtime.h>

typedef unsigned int u32;
typedef unsigned short u16;
typedef unsigned long long u64;
typedef __attribute__((ext_vector_type(8))) short bh8;   // 8 bf16 (4 VGPRs) MFMA frag
typedef __attribute__((ext_vector_type(4))) float f4;    // 4 fp32 acc

#define HMAX 1024   // max heavy (deg>S) nodes tracked; expected ~65
#define MAXD 128    // max out-degree bucketed; expected max ~58
#define SB_CAP 24576  // bin capacity: mean 16384, sigma ~127 -> +64 sigma
#define SBCHUNK 2048
#define SPLIT 8     // blocks per src bucket in shist/hfill
#define G1S 136     // gemm1 LDS row stride (128 + 8 pad)

__device__ inline f4 mfma16(bh8 a, bh8 b, f4 c) {
  return __builtin_amdgcn_mfma_f32_16x16x32_bf16(a, b, c, 0, 0, 0);
}

// ---------------- threefry2x32 (exact JAX cipher) ----------------
__host__ __device__ inline void tf2x32(u32 k0, u32 k1, u32 x0, u32 x1, u32& o0, u32& o1) {
  u32 ks2 = k0 ^ k1 ^ 0x1BD11BDAu;
#define ROTL32(x,d) (((x)<<(d))|((x)>>(32-(d))))
#define TFR(r) { x0 += x1; x1 = ROTL32(x1,(r)); x1 ^= x0; }
  x0 += k0; x1 += k1;
  TFR(13) TFR(15) TFR(26) TFR(6)
  x0 += k1; x1 += ks2 + 1u;
  TFR(17) TFR(29) TFR(16) TFR(24)
  x0 += ks2; x1 += k0 + 2u;
  TFR(13) TFR(15) TFR(26) TFR(6)
  x0 += k0; x1 += k1 + 3u;
  TFR(17) TFR(29) TFR(16) TFR(24)
  x0 += k1; x1 += ks2 + 4u;
  TFR(13) TFR(15) TFR(26) TFR(6)
  x0 += ks2; x1 += k0 + 5u;
  o0 = x0; o1 = x1;
#undef TFR
#undef ROTL32
}

__device__ inline u16 f2bf(float f) {      // round-to-nearest-even (finite inputs)
  u32 u = __float_as_uint(f);
  return (u16)((u + 0x7FFFu + ((u >> 16) & 1u)) >> 16);
}
__device__ inline float bflo(u32 u) { return __uint_as_float(u << 16); }
__device__ inline float bfhi(u32 u) { return __uint_as_float(u & 0xFFFF0000u); }

// ---------------- mega1: [bin blocks] || [gemm1 blocks] || [W2 prep block] ----------------
struct BinS { u32 lsrc[128]; u32 lbase[128]; u32 ldst[128]; u32 dbase[128]; };
struct GemS { u16 xs[64 * G1S]; u16 ws[64 * G1S]; };

__global__ __launch_bounds__(256) void k_mega1(const int* __restrict__ ei, int E,
                                               const float* __restrict__ x, int N,
                                               const float* __restrict__ W1, const float* __restrict__ W2,
                                               int* __restrict__ srcCnt, u32* __restrict__ srcRec,
                                               int* __restrict__ dstCnt, u64* __restrict__ dstRec,
                                               u16* __restrict__ h1b, u16* __restrict__ W2t, int nBin) {
  __shared__ __align__(16) char smem[sizeof(GemS)];
  int t = threadIdx.x;
  int bid = blockIdx.x;

  if (bid < nBin) {
    // ---- bin path: src-bin (u32) + dst-bin (u64) in one ei pass ----
    BinS& S = *(BinS*)smem;
    if (t < 128) { S.lsrc[t] = 0; S.ldst[t] = 0; }
    __syncthreads();
    int lo = bid * SBCHUNK;
    int hi = min(lo + SBCHUNK, E);
    int e0 = lo + 8 * t;
    int nv = min(8, hi - e0); if (nv < 0) nv = 0;
    int sv[8], dv[8];
    if (nv == 8 && ((E & 3) == 0)) {
      int4 a0 = *((const int4*)(ei + e0));
      int4 a1 = *((const int4*)(ei + e0 + 4));
      int4 b0 = *((const int4*)(ei + E + e0));
      int4 b1 = *((const int4*)(ei + E + e0 + 4));
      sv[0]=a0.x; sv[1]=a0.y; sv[2]=a0.z; sv[3]=a0.w; sv[4]=a1.x; sv[5]=a1.y; sv[6]=a1.z; sv[7]=a1.w;
      dv[0]=b0.x; dv[1]=b0.y; dv[2]=b0.z; dv[3]=b0.w; dv[4]=b1.x; dv[5]=b1.y; dv[6]=b1.z; dv[7]=b1.w;
    } else {
      for (int j = 0; j < nv; ++j) { sv[j] = ei[e0 + j]; dv[j] = ei[E + e0 + j]; }
    }
    for (int j = 0; j < nv; ++j) {
      atomicAdd(&S.lsrc[sv[j] >> 9], 1u);
      atomicAdd(&S.ldst[dv[j] >> 9], 1u);
    }
    __syncthreads();
    if (t < 128) {
      u32 c = S.lsrc[t];
      if (c) S.lbase[t] = (u32)atomicAdd(&srcCnt[t], (int)c);
      S.lsrc[t] = 0;
      u32 cd = S.ldst[t];
      if (cd) S.dbase[t] = (u32)atomicAdd(&dstCnt[t], (int)cd);
      S.ldst[t] = 0;
    }
    __syncthreads();
    for (int j = 0; j < nv; ++j) {
      int s = sv[j], d = dv[j];
      u32 i = (u32)(e0 + j);
      int bs = s >> 9;
      u32 slot = S.lbase[bs] + atomicAdd(&S.lsrc[bs], 1u);
      if (slot < SB_CAP) srcRec[(size_t)bs * SB_CAP + slot] = ((u32)(s & 511) << 21) | i;
      int bd = d >> 9;
      u32 slot2 = S.dbase[bd] + atomicAdd(&S.ldst[bd], 1u);
      if (slot2 < SB_CAP)
        dstRec[(size_t)bd * SB_CAP + slot2] = ((u64)(d & 511) << 37) | ((u64)(u32)s << 21) | i;
    }
  } else if (bid < 2 * nBin) {
    // ---- gemm1 path: h1 = bf16(x) @ bf16(W1), W1 transposed on the fly ----
    GemS& G = *(GemS*)smem;
    int wv = t >> 6, lane = t & 63;
    int qd = lane >> 4, md = lane & 15;
    int m0 = (bid - nBin) * 64;
    if (m0 >= N) return;
    f4 acc[4] = {};
    for (int ks = 0; ks < 256; ks += 128) {
      __syncthreads();
#pragma unroll
      for (int i = 0; i < 8; ++i) {             // stage x[m0..+63][ks..+127] -> bf16 LDS
        int f = t + 256 * i;                     // 2048 float4s
        int r = f >> 5, c4 = f & 31;
        int grow = m0 + r; if (grow >= N) grow = N - 1;
        float4 v = ((const float4*)x)[(size_t)grow * 64 + (ks >> 2) + c4];
        u32 p0 = (u32)f2bf(v.x) | ((u32)f2bf(v.y) << 16);
        u32 p1 = (u32)f2bf(v.z) | ((u32)f2bf(v.w) << 16);
        *((uint2*)(G.xs + r * G1S + c4 * 4)) = make_uint2(p0, p1);
      }
#pragma unroll
      for (int i = 0; i < 8; ++i) {             // stage W1[ks..+127][0..63] fp32 -> bf16 n-major
        int f = t + 256 * i;                     // 2048 float4s (128k x 16 cols)
        int k = f >> 4, c4 = f & 15;
        float4 v = ((const float4*)W1)[(ks + k) * 16 + c4];
        int n0 = c4 * 4;
        G.ws[(n0 + 0) * G1S + k] = f2bf(v.x);
        G.ws[(n0 + 1) * G1S + k] = f2bf(v.y);
        G.ws[(n0 + 2) * G1S + k] = f2bf(v.z);
        G.ws[(n0 + 3) * G1S + k] = f2bf(v.w);
      }
      __syncthreads();
#pragma unroll
      for (int kk = 0; kk < 128; kk += 32) {
        bh8 af = *((const bh8*)(G.xs + (16 * wv + md) * G1S + kk + qd * 8));
#pragma unroll
        for (int nt = 0; nt < 4; ++nt) {
          bh8 bf = *((const bh8*)(G.ws + (nt * 16 + md) * G1S + kk + qd * 8));
          acc[nt] = mfma16(af, bf, acc[nt]);
        }
      }
    }
#pragma unroll
    for (int nt = 0; nt < 4; ++nt)
#pragma unroll
      for (int r = 0; r < 4; ++r) {
        int row = m0 + 16 * wv + qd * 4 + r;
        if (row < N) h1b[(size_t)row * 64 + nt * 16 + md] = f2bf(acc[nt][r]);
      }
  } else {
    // ---- W2 prep path: W2t[n][k] = bf16(W2[k][n]) ----
    for (int e = t; e < 64 * 128; e += 256) {
      int n = e & 127, k = e >> 7;
      W2t[n * 64 + k] = f2bf(W2[k * 128 + n]);
    }
  }
}

// ---------------- shist: partial LDS histograms -> global outdegB ----------------
__global__ __launch_bounds__(256) void k_shist(const int* __restrict__ srcCnt, const u32* __restrict__ srcRec,
                                               int* __restrict__ outdegB) {
  int bk = blockIdx.x >> 3;          // / SPLIT
  int part = blockIdx.x & (SPLIT - 1);
  int total = min(srcCnt[bk], SB_CAP);
  int lo = total * part / SPLIT;
  int hi = total * (part + 1) / SPLIT;
  __shared__ u32 cnt[512];
  int t = threadIdx.x;
  cnt[t] = 0; cnt[t + 256] = 0;
  __syncthreads();
  const u32* R = srcRec + (size_t)bk * SB_CAP;
  for (int i = lo + t; i < hi; i += 256) atomicAdd(&cnt[R[i] >> 21], 1u);
  __syncthreads();
  int base = bk * 512;
  for (int v = t; v < 512; v += 256) {
    u32 c = cnt[v];
    if (c) atomicAdd(&outdegB[base + v], (int)c);
  }
}

// ---------------- hdetect: heavy-id assignment + dst-bucket scan ----------------
__global__ __launch_bounds__(256) void k_hdetect(const int* __restrict__ outdegB, u32* __restrict__ idAB,
                                                 int* __restrict__ hcA, int* __restrict__ hcB,
                                                 const int* __restrict__ dstCnt, int* __restrict__ bucketBase,
                                                 int* __restrict__ dptr, int nb, int N) {
  if (blockIdx.x == 0 && threadIdx.x == 0) {
    int s = 0;
    for (int i = 0; i < nb; ++i) { bucketBase[i] = s; s += min(dstCnt[i], SB_CAP); }
    bucketBase[nb] = s;
    dptr[N] = s;   // == E (absent overflow)
  }
  int v = blockIdx.x * 256 + threadIdx.x;
  if (v >= N) return;
  int dg = outdegB[v];
  u32 pk = 0;
  if (dg > 50) {
    int idb = atomicAdd(hcB, 1);
    if (idb < HMAX) pk = (u32)(idb + 1);
    if (dg > 100) {
      int ida = atomicAdd(hcA, 1);
      if (ida < HMAX) pk |= (u32)(ida + 1) << 16;
    }
  }
  idAB[v] = pk;
}

// ---------------- hfill: PRNG-bucket heavy edges ----------------
__global__ __launch_bounds__(256) void k_hfill(const int* __restrict__ srcCnt, const u32* __restrict__ srcRec,
                                               const u32* __restrict__ idAB,
                                               int* __restrict__ bcA, u64* __restrict__ bukA,
                                               int* __restrict__ bcB, u64* __restrict__ bukB,
                                               u32 kaA, u32 kbA, u32 kaB, u32 kbB) {
  int bk = blockIdx.x >> 3;
  int part = blockIdx.x & (SPLIT - 1);
  int total = min(srcCnt[bk], SB_CAP);
  int lo = total * part / SPLIT;
  int hi = total * (part + 1) / SPLIT;
  const u32* R = srcRec + (size_t)bk * SB_CAP;
  int base = bk * 512;
  for (int i = lo + threadIdx.x; i < hi; i += 256) {
    u32 r = R[i];
    u32 pk = idAB[base + (int)(r >> 21)];
    if (pk) {
      u32 e = r & 0x1FFFFFu;
      int idb = (int)(pk & 0xFFFFu) - 1;
      if (idb >= 0) {
        u32 w0, w1; tf2x32(kaB, kbB, 0u, e, w0, w1);
        int slot = atomicAdd(&bcB[idb], 1);
        if (slot < MAXD) bukB[(size_t)idb * MAXD + slot] = ((u64)((w0 ^ w1) >> 9) << 32) | e;
      }
      int ida = (int)(pk >> 16) - 1;
      if (ida >= 0) {
        u32 w0, w1; tf2x32(kaA, kbA, 0u, e, w0, w1);
        int slot = atomicAdd(&bcA[ida], 1);
        if (slot < MAXD) bukA[(size_t)ida * MAXD + slot] = ((u64)((w0 ^ w1) >> 9) << 32) | e;
      }
    }
  }
}

// ---------------- rank (both phases in one launch): drop rank >= S ----------------
__global__ __launch_bounds__(256) void k_rank2(const int* __restrict__ hcA, const int* __restrict__ bcA,
                                               const u64* __restrict__ bukA,
                                               const int* __restrict__ hcB, const int* __restrict__ bcB,
                                               const u64* __restrict__ bukB,
                                               unsigned char* __restrict__ mask) {
  bool isA = blockIdx.x < (HMAX / 4);
  int bx = isA ? blockIdx.x : blockIdx.x - HMAX / 4;
  const int* hcount = isA ? hcA : hcB;
  const int* bcount = isA ? bcA : bcB;
  const u64* bucket = isA ? bukA : bukB;
  int S = isA ? 100 : 50;
  int bit = isA ? 1 : 2;
  int wid = (bx * 256 + (int)threadIdx.x) >> 6;
  int lane = threadIdx.x & 63;
  int hc = hcount[0]; if (hc > HMAX) hc = HMAX;
  if (wid >= hc) return;
  int d = bcount[wid]; if (d > MAXD) d = MAXD;
  const u64* B = bucket + (size_t)wid * MAXD;
  for (int i = lane; i < d; i += 64) {
    u64 ki = B[i];
    int rank = 0;
    for (int j = 0; j < d; ++j) rank += (B[j] < ki) ? 1 : 0;
    if (rank >= S) {
      u32 e = (u32)ki;
      mask[e] = (unsigned char)(mask[e] & ~bit);
    }
  }
}

// ---------------- phase2: per-bucket counting sort from dstRec -> entries/dptr/dinv ----------------
// dstRec = dstlow(37:45) | src(21:36) | eid(0:20); mask gathered by eid
__global__ __launch_bounds__(256) void k_phase2(const int* __restrict__ bucketBase,
                                                const int* __restrict__ dstCnt,
                                                const u64* __restrict__ dstRec,
                                                const unsigned char* __restrict__ mask,
                                                u32* __restrict__ entries, int* __restrict__ dptr,
                                                float* __restrict__ dinv1, float* __restrict__ dinv2, int N) {
  int b = blockIdx.x;
  int base = bucketBase[b];
  int cnt0 = min(dstCnt[b], SB_CAP);
  const u64* R = dstRec + (size_t)b * SB_CAP;
  __shared__ u32 cnt[512];
  __shared__ u32 ws4[4];
  int t = threadIdx.x;
  cnt[t] = 0; cnt[t + 256] = 0;
  __syncthreads();
  for (int i = t; i < cnt0; i += 256) {
    u64 r = R[i];
    u32 dl = (u32)(r >> 37) & 511u;
    u32 m = mask[(u32)r & 0x1FFFFFu];
    u32 add = 1u + ((m & 1u) << 10) + (((m >> 1) & 1u) << 20);
    atomicAdd(&cnt[dl], add);
  }
  __syncthreads();
  u32 c0 = cnt[2 * t], c1 = cnt[2 * t + 1];
  u32 n0 = c0 & 1023u, n1 = c1 & 1023u;
  u32 pair = n0 + n1;
  int lane = t & 63, w = t >> 6;
  u32 incl = pair;
  for (int off = 1; off < 64; off <<= 1) {
    u32 nbv = (u32)__shfl_up((int)incl, off, 64);
    if (lane >= off) incl += nbv;
  }
  if (lane == 63) ws4[w] = incl;
  __syncthreads();
  if (t == 0) { u32 s = 0; for (int k = 0; k < 4; ++k) { u32 x = ws4[k]; ws4[k] = s; s += x; } }
  __syncthreads();
  u32 excl = incl - pair + ws4[w];
  int v0 = b * 512 + 2 * t;
  if (v0 < N) {
    dptr[v0] = base + (int)excl;
    dinv1[v0] = 1.0f / sqrtf((float)(((c0 >> 10) & 1023u) + 1u));
    dinv2[v0] = 1.0f / sqrtf((float)(((c0 >> 20) & 1023u) + 1u));
  }
  if (v0 + 1 < N) {
    dptr[v0 + 1] = base + (int)(excl + n0);
    dinv1[v0 + 1] = 1.0f / sqrtf((float)(((c1 >> 10) & 1023u) + 1u));
    dinv2[v0 + 1] = 1.0f / sqrtf((float)(((c1 >> 20) & 1023u) + 1u));
  }
  __syncthreads();
  cnt[2 * t] = excl;
  cnt[2 * t + 1] = excl + n0;
  __syncthreads();
  for (int i = t; i < cnt0; i += 256) {
    u64 r = R[i];
    u32 dl = (u32)(r >> 37) & 511u;
    u32 m = mask[(u32)r & 0x1FFFFFu];
    u32 src = (u32)(r >> 21) & 0xFFFFu;
    u32 slot = atomicAdd(&cnt[dl], 1u);
    entries[base + slot] = src | ((m & 1u) ? (1u << 30) : 0u) | ((m & 2u) ? (1u << 31) : 0u);
  }
}

// ---------------- conv1: aggregate h1 + bias + relu + L2 normalize -> bf16 hnb ----------------
// wave per dst; eighth-wave: 8 lanes x uint4(16B) = 128B row, 8 rows in flight + 1-deep pipeline
__global__ __launch_bounds__(256) void k_conv1n(const int* __restrict__ ptr, const u32* __restrict__ entries,
                                                const float* __restrict__ dinv1, const uint4* __restrict__ h1q,
                                                const float* __restrict__ b1, uint4* __restrict__ hnbq, int N) {
  int wid = (blockIdx.x * 256 + threadIdx.x) >> 6;
  if (wid >= N) return;
  int lane = threadIdx.x & 63;
  int lo8 = lane & 7, grp = lane >> 3;
  int beg = ptr[wid], end = ptr[wid + 1];
  float a0 = 0.f, a1 = 0.f, a2 = 0.f, a3 = 0.f, a4 = 0.f, a5 = 0.f, a6 = 0.f, a7 = 0.f;
  for (int cb = beg; cb < end; cb += 64) {
    int idx = cb + lane;
    float wgt = 0.f; int s = 0;
    if (idx < end) {
      u32 e = entries[idx];
      s = (int)(e & 0xFFFFu);
      if (e & (1u << 30)) wgt = dinv1[s];
    }
    int nq = (min(64, end - cb) + 7) >> 3;
    int j = grp;
    float w = __shfl(wgt, j, 64);
    int sj = __shfl(s, j, 64);
    uint4 uv = h1q[(size_t)sj * 8 + lo8];
    for (int i = 1; i < nq; ++i) {
      int j2 = j + 8;
      float w2 = __shfl(wgt, j2, 64);
      int s2 = __shfl(s, j2, 64);
      uint4 uv2 = h1q[(size_t)s2 * 8 + lo8];
      a0 = fmaf(w, bflo(uv.x), a0); a1 = fmaf(w, bfhi(uv.x), a1);
      a2 = fmaf(w, bflo(uv.y), a2); a3 = fmaf(w, bfhi(uv.y), a3);
      a4 = fmaf(w, bflo(uv.z), a4); a5 = fmaf(w, bfhi(uv.z), a5);
      a6 = fmaf(w, bflo(uv.w), a6); a7 = fmaf(w, bfhi(uv.w), a7);
      w = w2; uv = uv2; j = j2;
    }
    a0 = fmaf(w, bflo(uv.x), a0); a1 = fmaf(w, bfhi(uv.x), a1);
    a2 = fmaf(w, bflo(uv.y), a2); a3 = fmaf(w, bfhi(uv.y), a3);
    a4 = fmaf(w, bflo(uv.z), a4); a5 = fmaf(w, bfhi(uv.z), a5);
    a6 = fmaf(w, bflo(uv.w), a6); a7 = fmaf(w, bfhi(uv.w), a7);
  }
#pragma unroll
  for (int off = 8; off < 64; off <<= 1) {
    a0 += __shfl_xor(a0, off, 64); a1 += __shfl_xor(a1, off, 64);
    a2 += __shfl_xor(a2, off, 64); a3 += __shfl_xor(a3, off, 64);
    a4 += __shfl_xor(a4, off, 64); a5 += __shfl_xor(a5, off, 64);
    a6 += __shfl_xor(a6, off, 64); a7 += __shfl_xor(a7, off, 64);
  }
  float dv = dinv1[wid];
  uint4 uo = h1q[(size_t)wid * 8 + lo8];
  a0 = fmaf(dv, bflo(uo.x), a0); a1 = fmaf(dv, bfhi(uo.x), a1);
  a2 = fmaf(dv, bflo(uo.y), a2); a3 = fmaf(dv, bfhi(uo.y), a3);
  a4 = fmaf(dv, bflo(uo.z), a4); a5 = fmaf(dv, bfhi(uo.z), a5);
  a6 = fmaf(dv, bflo(uo.w), a6); a7 = fmaf(dv, bfhi(uo.w), a7);
  float4 bbA = ((const float4*)b1)[lo8 * 2];
  float4 bbB = ((const float4*)b1)[lo8 * 2 + 1];
  float o0 = fmaxf(fmaf(dv, a0, bbA.x), 0.f);
  float o1 = fmaxf(fmaf(dv, a1, bbA.y), 0.f);
  float o2 = fmaxf(fmaf(dv, a2, bbA.z), 0.f);
  float o3 = fmaxf(fmaf(dv, a3, bbA.w), 0.f);
  float o4 = fmaxf(fmaf(dv, a4, bbB.x), 0.f);
  float o5 = fmaxf(fmaf(dv, a5, bbB.y), 0.f);
  float o6 = fmaxf(fmaf(dv, a6, bbB.z), 0.f);
  float o7 = fmaxf(fmaf(dv, a7, bbB.w), 0.f);
  float ss = fmaf(o0, o0, fmaf(o1, o1, fmaf(o2, o2, o3 * o3)))
           + fmaf(o4, o4, fmaf(o5, o5, fmaf(o6, o6, o7 * o7)));
#pragma unroll
  for (int off = 1; off < 8; off <<= 1) ss += __shfl_xor(ss, off, 8);
  float sc = 1.f / fmaxf(sqrtf(ss), 1e-12f);
  if (lane < 8) {
    uint4 pv;
    pv.x = (u32)f2bf(o0 * sc) | ((u32)f2bf(o1 * sc) << 16);
    pv.y = (u32)f2bf(o2 * sc) | ((u32)f2bf(o3 * sc) << 16);
    pv.z = (u32)f2bf(o4 * sc) | ((u32)f2bf(o5 * sc) << 16);
    pv.w = (u32)f2bf(o6 * sc) | ((u32)f2bf(o7 * sc) << 16);
    hnbq[(size_t)wid * 8 + lo8] = pv;
  }
}

// ---------------- agg2: aggregate hnb with dinv2 -> bf16 agg2b ----------------
__global__ __launch_bounds__(256) void k_agg2(const int* __restrict__ ptr, const u32* __restrict__ entries,
                                              const float* __restrict__ dinv2, const uint4* __restrict__ hnq,
                                              uint4* __restrict__ agg2q, int N) {
  int wid = (blockIdx.x * 256 + threadIdx.x) >> 6;
  if (wid >= N) return;
  int lane = threadIdx.x & 63;
  int lo8 = lane & 7, grp = lane >> 3;
  int beg = ptr[wid], end = ptr[wid + 1];
  float a0 = 0.f, a1 = 0.f, a2 = 0.f, a3 = 0.f, a4 = 0.f, a5 = 0.f, a6 = 0.f, a7 = 0.f;
  for (int cb = beg; cb < end; cb += 64) {
    int idx = cb + lane;
    float wgt = 0.f; int s = 0;
    if (idx < end) {
      u32 e = entries[idx];
      s = (int)(e & 0xFFFFu);
      if (e & (1u << 31)) wgt = dinv2[s];
    }
    int nq = (min(64, end - cb) + 7) >> 3;
    int j = grp;
    float w = __shfl(wgt, j, 64);
    int sj = __shfl(s, j, 64);
    uint4 uv = hnq[(size_t)sj * 8 + lo8];
    for (int i = 1; i < nq; ++i) {
      int j2 = j + 8;
      float w2 = __shfl(wgt, j2, 64);
      int s2 = __shfl(s, j2, 64);
      uint4 uv2 = hnq[(size_t)s2 * 8 + lo8];
      a0 = fmaf(w, bflo(uv.x), a0); a1 = fmaf(w, bfhi(uv.x), a1);
      a2 = fmaf(w, bflo(uv.y), a2); a3 = fmaf(w, bfhi(uv.y), a3);
      a4 = fmaf(w, bflo(uv.z), a4); a5 = fmaf(w, bfhi(uv.z), a5);
      a6 = fmaf(w, bflo(uv.w), a6); a7 = fmaf(w, bfhi(uv.w), a7);
      w = w2; uv = uv2; j = j2;
    }
    a0 = fmaf(w, bflo(uv.x), a0); a1 = fmaf(w, bfhi(uv.x), a1);
    a2 = fmaf(w, bflo(uv.y), a2); a3 = fmaf(w, bfhi(uv.y), a3);
    a4 = fmaf(w, bflo(uv.z), a4); a5 = fmaf(w, bfhi(uv.z), a5);
    a6 = fmaf(w, bflo(uv.w), a6); a7 = fmaf(w, bfhi(uv.w), a7);
  }
#pragma unroll
  for (int off = 8; off < 64; off <<= 1) {
    a0 += __shfl_xor(a0, off, 64); a1 += __shfl_xor(a1, off, 64);
    a2 += __shfl_xor(a2, off, 64); a3 += __shfl_xor(a3, off, 64);
    a4 += __shfl_xor(a4, off, 64); a5 += __shfl_xor(a5, off, 64);
    a6 += __shfl_xor(a6, off, 64); a7 += __shfl_xor(a7, off, 64);
  }
  float dv = dinv2[wid];
  uint4 uo = hnq[(size_t)wid * 8 + lo8];
  a0 = fmaf(dv, bflo(uo.x), a0); a1 = fmaf(dv, bfhi(uo.x), a1);
  a2 = fmaf(dv, bflo(uo.y), a2); a3 = fmaf(dv, bfhi(uo.y), a3);
  a4 = fmaf(dv, bflo(uo.z), a4); a5 = fmaf(dv, bfhi(uo.z), a5);
  a6 = fmaf(dv, bflo(uo.w), a6); a7 = fmaf(dv, bfhi(uo.w), a7);
  if (lane < 8) {
    uint4 pv;
    pv.x = (u32)f2bf(dv * a0) | ((u32)f2bf(dv * a1) << 16);
    pv.y = (u32)f2bf(dv * a2) | ((u32)f2bf(dv * a3) << 16);
    pv.z = (u32)f2bf(dv * a4) | ((u32)f2bf(dv * a5) << 16);
    pv.w = (u32)f2bf(dv * a6) | ((u32)f2bf(dv * a7) << 16);
    agg2q[(size_t)wid * 8 + lo8] = pv;
  }
}

// ---------------- gemm2f: out = agg2b @ W2 + b2 (MFMA, fused bias, fp32 out) ----------------
#define G2S 72
__global__ __launch_bounds__(256) void k_gemm2f(const u16* __restrict__ aggb, const u16* __restrict__ W2t,
                                                const float* __restrict__ b2, float* __restrict__ out, int N) {
  __shared__ u16 hs[64 * G2S];
  __shared__ u16 ws[128 * G2S];
  int t = threadIdx.x;
  int wv = t >> 6, lane = t & 63;
  int qd = lane >> 4, md = lane & 15;
  int m0 = blockIdx.x * 64;
#pragma unroll
  for (int i = 0; i < 2; ++i) {                 // stage aggb: 64 rows x 64 u16 = 512 uint4
    int cc = t + 256 * i;
    int r = cc >> 3, kc = (cc & 7) * 8;
    int grow = m0 + r; if (grow >= N) grow = N - 1;
    *((uint4*)(hs + r * G2S + kc)) = *((const uint4*)(aggb + (size_t)grow * 64 + kc));
  }
#pragma unroll
  for (int i = 0; i < 4; ++i) {                 // stage W2t (128x64 u16)
    int cc = t + 256 * i;
    int n = cc >> 3, kc = (cc & 7) * 8;
    *((uint4*)(ws + n * G2S + kc)) = *((const uint4*)(W2t + n * 64 + kc));
  }
  __syncthreads();
  f4 acc[8] = {};
#pragma unroll
  for (int kk = 0; kk < 64; kk += 32) {
    bh8 af = *((const bh8*)(hs + (16 * wv + md) * G2S + kk + qd * 8));
#pragma unroll
    for (int nt = 0; nt < 8; ++nt) {
      bh8 bf = *((const bh8*)(ws + (nt * 16 + md) * G2S + kk + qd * 8));
      acc[nt] = mfma16(af, bf, acc[nt]);
    }
  }
#pragma unroll
  for (int nt = 0; nt < 8; ++nt) {
    float bv = b2[nt * 16 + md];
#pragma unroll
    for (int r = 0; r < 4; ++r) {
      int row = m0 + 16 * wv + qd * 4 + r;
      if (row < N) out[(size_t)row * 128 + nt * 16 + md] = acc[nt][r] + bv;
    }
  }
}

// ---------------- launch ----------------
extern "C" void kernel_launch(void* const* d_in, const int* in_sizes, int n_in,
                              void* d_out, int out_size, void* d_ws, size_t ws_size,
                              hipStream_t stream) {
  const float* x  = (const float*)d_in[0];
  const int*   ei = (const int*)d_in[1];
  const float* W1 = (const float*)d_in[2];
  const float* b1 = (const float*)d_in[3];
  const float* W2 = (const float*)d_in[4];
  const float* b2 = (const float*)d_in[5];
  const int N = in_sizes[0] / 256;
  const int E = in_sizes[1] / 2;
  const int nb = (N + 511) >> 9;   // buckets (98 for N=50000; code assumes <=128)

  u32 sk1a, sk1b, sk2a, sk2b;
  tf2x32(0u, 42u, 0u, 0u, sk1a, sk1b);
  tf2x32(0u, 42u, 0u, 1u, sk2a, sk2b);

  char* p = (char*)d_ws;
  auto alloc = [&](size_t bytes) { char* r = p; p += (bytes + 255) & ~(size_t)255; return r; };
  // --- zero-init group (contiguous) ---
  int* dstCnt      = (int*)alloc(128 * 4);
  int* srcCnt      = (int*)alloc(128 * 4);
  int* hcbA        = (int*)alloc((size_t)(1 + HMAX) * 4);
  int* hcbB        = (int*)alloc((size_t)(1 + HMAX) * 4);
  int* outdegB     = (int*)alloc((size_t)nb * 512 * 4);
  char* zero_end = p;
  // --- rest ---
  unsigned char* mask = (unsigned char*)alloc((size_t)E);
  u32* idAB     = (u32*)alloc((size_t)nb * 512 * 4);
  u16* h1b      = (u16*)alloc((size_t)N * 64 * 2);
  u16* hnb      = (u16*)alloc((size_t)N * 64 * 2);
  u16* agg2b    = (u16*)alloc((size_t)N * 64 * 2);
  float* dinv1  = (float*)alloc((size_t)N * 4);
  float* dinv2  = (float*)alloc((size_t)N * 4);
  int* dptr     = (int*)alloc((size_t)(N + 1) * 4);
  int* bucketBase = (int*)alloc(129 * 4);
  u32* entries  = (u32*)alloc((size_t)E * 4);
  u32* srcRec   = (u32*)alloc((size_t)nb * SB_CAP * 4);
  u64* dstRec   = (u64*)alloc((size_t)nb * SB_CAP * 8);
  u64* bukA     = (u64*)alloc((size_t)HMAX * MAXD * 8);
  u64* bukB     = (u64*)alloc((size_t)HMAX * MAXD * 8);
  u16* W2t      = (u16*)alloc(64 * 128 * 2);

  int* hcA = hcbA; int* bcA = hcbA + 1;
  int* hcB = hcbB; int* bcB = hcbB + 1;

  hipMemsetAsync(dstCnt, 0x00, (size_t)(zero_end - (char*)dstCnt), stream);
  hipMemsetAsync(mask, 0x03, (size_t)E, stream);

  const int nBin = (E + SBCHUNK - 1) / SBCHUNK;
  const int nGemm = (N + 63) / 64;
  k_mega1<<<nBin + nGemm + 1, 256, 0, stream>>>(ei, E, x, N, W1, W2,
                                                srcCnt, srcRec, dstCnt, dstRec, h1b, W2t, nBin);
  k_shist<<<nb * SPLIT, 256, 0, stream>>>(srcCnt, srcRec, outdegB);
  k_hdetect<<<(N + 255) / 256, 256, 0, stream>>>(outdegB, idAB, hcA, hcB, dstCnt, bucketBase,
                                                 dptr, nb, N);
  k_hfill<<<nb * SPLIT, 256, 0, stream>>>(srcCnt, srcRec, idAB, bcA, bukA, bcB, bukB,
                                          sk1a, sk1b, sk2a, sk2b);
  k_rank2<<<HMAX / 2, 256, 0, stream>>>(hcA, bcA, bukA, hcB, bcB, bukB, mask);
  k_phase2<<<nb, 256, 0, stream>>>(bucketBase, dstCnt, dstRec, mask, entries, dptr,
                                   dinv1, dinv2, N);
  k_conv1n<<<(N * 64 + 255) / 256, 256, 0, stream>>>(dptr, entries, dinv1, (const uint4*)h1b, b1,
                                                     (uint4*)hnb, N);
  k_agg2<<<(N * 64 + 255) / 256, 256, 0, stream>>>(dptr, entries, dinv2, (const uint4*)hnb,
                                                   (uint4*)agg2b, N);
  k_gemm2f<<<(N + 63) / 64, 256, 0, stream>>>(agg2b, W2t, b2, (float*)d_out, N);
}

// Round 9
// 304.482 us; speedup vs baseline: 1.0949x; 1.0949x over previous
//
#include <hip/hip_runtime.h>

typedef unsigned int u32;
typedef unsigned short u16;
typedef unsigned long long u64;
typedef __attribute__((ext_vector_type(8))) short bh8;   // 8 bf16 (4 VGPRs) MFMA frag
typedef __attribute__((ext_vector_type(4))) float f4;    // 4 fp32 acc

#define HMAX 1024    // max heavy (deg>S) nodes tracked; expected ~65
#define MAXD 128     // max out-degree bucketed; expected max ~58
#define SB_CAP 24576 // src-bin capacity: mean 16384, sigma ~127 -> +64 sigma
#define DB_CAP 6144  // dst-bin capacity: mean 4092, sigma ~64 -> +32 sigma
#define SBCHUNK 2048
#define SPLIT 8      // blocks per src bucket in shist/hfill
#define G1S 136      // gemm1 LDS row stride (128 + 8 pad)
#define DROP_CAP 32768

__device__ inline f4 mfma16(bh8 a, bh8 b, f4 c) {
  return __builtin_amdgcn_mfma_f32_16x16x32_bf16(a, b, c, 0, 0, 0);
}

// ---------------- threefry2x32 (exact JAX cipher) ----------------
__host__ __device__ inline void tf2x32(u32 k0, u32 k1, u32 x0, u32 x1, u32& o0, u32& o1) {
  u32 ks2 = k0 ^ k1 ^ 0x1BD11BDAu;
#define ROTL32(x,d) (((x)<<(d))|((x)>>(32-(d))))
#define TFR(r) { x0 += x1; x1 = ROTL32(x1,(r)); x1 ^= x0; }
  x0 += k0; x1 += k1;
  TFR(13) TFR(15) TFR(26) TFR(6)
  x0 += k1; x1 += ks2 + 1u;
  TFR(17) TFR(29) TFR(16) TFR(24)
  x0 += ks2; x1 += k0 + 2u;
  TFR(13) TFR(15) TFR(26) TFR(6)
  x0 += k0; x1 += k1 + 3u;
  TFR(17) TFR(29) TFR(16) TFR(24)
  x0 += k1; x1 += ks2 + 4u;
  TFR(13) TFR(15) TFR(26) TFR(6)
  x0 += ks2; x1 += k0 + 5u;
  o0 = x0; o1 = x1;
#undef TFR
#undef ROTL32
}

__device__ inline u16 f2bf(float f) {      // round-to-nearest-even (finite inputs)
  u32 u = __float_as_uint(f);
  return (u16)((u + 0x7FFFu + ((u >> 16) & 1u)) >> 16);
}
__device__ inline float bflo(u32 u) { return __uint_as_float(u << 16); }
__device__ inline float bfhi(u32 u) { return __uint_as_float(u & 0xFFFF0000u); }

// ---------------- mega1: [bin blocks] || [gemm1 blocks] || [W2 prep block] ----------------
// src bins: 128 x 512 nodes (outdeg machinery); dst bins: up to 512 x 128 nodes (CSR sort)
struct BinS { u32 lsrc[128]; u32 lbase[128]; u32 ldst[512]; u32 dbase[512]; };
struct GemS { u16 xs[64 * G1S]; u16 ws[64 * G1S]; };

__global__ __launch_bounds__(256) void k_mega1(const int* __restrict__ ei, int E,
                                               const float* __restrict__ x, int N,
                                               const float* __restrict__ W1, const float* __restrict__ W2,
                                               int* __restrict__ srcCnt, u32* __restrict__ srcRec,
                                               int* __restrict__ dstCnt, u64* __restrict__ dstRec,
                                               u16* __restrict__ h1b, u16* __restrict__ W2t, int nBin) {
  __shared__ __align__(16) char smem[sizeof(GemS)];
  int t = threadIdx.x;
  int bid = blockIdx.x;

  if (bid < nBin) {
    // ---- bin path: src-bin (u32) + dst-bin (u64) in one ei pass ----
    BinS& S = *(BinS*)smem;
    if (t < 128) S.lsrc[t] = 0;
    for (int v = t; v < 512; v += 256) S.ldst[v] = 0;
    __syncthreads();
    int lo = bid * SBCHUNK;
    int hi = min(lo + SBCHUNK, E);
    int e0 = lo + 8 * t;
    int nv = min(8, hi - e0); if (nv < 0) nv = 0;
    int sv[8], dv[8];
    if (nv == 8 && ((E & 3) == 0)) {
      int4 a0 = *((const int4*)(ei + e0));
      int4 a1 = *((const int4*)(ei + e0 + 4));
      int4 b0 = *((const int4*)(ei + E + e0));
      int4 b1 = *((const int4*)(ei + E + e0 + 4));
      sv[0]=a0.x; sv[1]=a0.y; sv[2]=a0.z; sv[3]=a0.w; sv[4]=a1.x; sv[5]=a1.y; sv[6]=a1.z; sv[7]=a1.w;
      dv[0]=b0.x; dv[1]=b0.y; dv[2]=b0.z; dv[3]=b0.w; dv[4]=b1.x; dv[5]=b1.y; dv[6]=b1.z; dv[7]=b1.w;
    } else {
      for (int j = 0; j < nv; ++j) { sv[j] = ei[e0 + j]; dv[j] = ei[E + e0 + j]; }
    }
    for (int j = 0; j < nv; ++j) {
      atomicAdd(&S.lsrc[sv[j] >> 9], 1u);
      atomicAdd(&S.ldst[dv[j] >> 7], 1u);
    }
    __syncthreads();
    if (t < 128) {
      u32 c = S.lsrc[t];
      if (c) S.lbase[t] = (u32)atomicAdd(&srcCnt[t], (int)c);
      S.lsrc[t] = 0;
    }
    for (int v = t; v < 512; v += 256) {
      u32 cd = S.ldst[v];
      if (cd) S.dbase[v] = (u32)atomicAdd(&dstCnt[v], (int)cd);
      S.ldst[v] = 0;
    }
    __syncthreads();
    for (int j = 0; j < nv; ++j) {
      int s = sv[j], d = dv[j];
      u32 i = (u32)(e0 + j);
      int bs = s >> 9;
      u32 slot = S.lbase[bs] + atomicAdd(&S.lsrc[bs], 1u);
      if (slot < SB_CAP) srcRec[(size_t)bs * SB_CAP + slot] = ((u32)(s & 511) << 21) | i;
      int bd = d >> 7;
      u32 slot2 = S.dbase[bd] + atomicAdd(&S.ldst[bd], 1u);
      if (slot2 < DB_CAP)
        dstRec[(size_t)bd * DB_CAP + slot2] = ((u64)(d & 127) << 37) | ((u64)(u32)s << 21) | i;
    }
  } else if (bid < 2 * nBin) {
    // ---- gemm1 path: h1 = bf16(x) @ bf16(W1), W1 transposed on the fly ----
    GemS& G = *(GemS*)smem;
    int wv = t >> 6, lane = t & 63;
    int qd = lane >> 4, md = lane & 15;
    int m0 = (bid - nBin) * 64;
    if (m0 >= N) return;
    f4 acc[4] = {};
    for (int ks = 0; ks < 256; ks += 128) {
      __syncthreads();
#pragma unroll
      for (int i = 0; i < 8; ++i) {             // stage x[m0..+63][ks..+127] -> bf16 LDS
        int f = t + 256 * i;                     // 2048 float4s
        int r = f >> 5, c4 = f & 31;
        int grow = m0 + r; if (grow >= N) grow = N - 1;
        float4 v = ((const float4*)x)[(size_t)grow * 64 + (ks >> 2) + c4];
        u32 p0 = (u32)f2bf(v.x) | ((u32)f2bf(v.y) << 16);
        u32 p1 = (u32)f2bf(v.z) | ((u32)f2bf(v.w) << 16);
        *((uint2*)(G.xs + r * G1S + c4 * 4)) = make_uint2(p0, p1);
      }
#pragma unroll
      for (int i = 0; i < 8; ++i) {             // stage W1[ks..+127][0..63] fp32 -> bf16 n-major
        int f = t + 256 * i;
        int k = f >> 4, c4 = f & 15;
        float4 v = ((const float4*)W1)[(ks + k) * 16 + c4];
        int n0 = c4 * 4;
        G.ws[(n0 + 0) * G1S + k] = f2bf(v.x);
        G.ws[(n0 + 1) * G1S + k] = f2bf(v.y);
        G.ws[(n0 + 2) * G1S + k] = f2bf(v.z);
        G.ws[(n0 + 3) * G1S + k] = f2bf(v.w);
      }
      __syncthreads();
#pragma unroll
      for (int kk = 0; kk < 128; kk += 32) {
        bh8 af = *((const bh8*)(G.xs + (16 * wv + md) * G1S + kk + qd * 8));
#pragma unroll
        for (int nt = 0; nt < 4; ++nt) {
          bh8 bf = *((const bh8*)(G.ws + (nt * 16 + md) * G1S + kk + qd * 8));
          acc[nt] = mfma16(af, bf, acc[nt]);
        }
      }
    }
#pragma unroll
    for (int nt = 0; nt < 4; ++nt)
#pragma unroll
      for (int r = 0; r < 4; ++r) {
        int row = m0 + 16 * wv + qd * 4 + r;
        if (row < N) h1b[(size_t)row * 64 + nt * 16 + md] = f2bf(acc[nt][r]);
      }
  } else {
    // ---- W2 prep path: W2t[n][k] = bf16(W2[k][n]) ----
    for (int e = t; e < 64 * 128; e += 256) {
      int n = e & 127, k = e >> 7;
      W2t[n * 64 + k] = f2bf(W2[k * 128 + n]);
    }
  }
}

// ---------------- shist: partial LDS histograms -> global outdegB ----------------
__global__ __launch_bounds__(256) void k_shist(const int* __restrict__ srcCnt, const u32* __restrict__ srcRec,
                                               int* __restrict__ outdegB) {
  int bk = blockIdx.x >> 3;          // / SPLIT
  int part = blockIdx.x & (SPLIT - 1);
  int total = min(srcCnt[bk], SB_CAP);
  int lo = total * part / SPLIT;
  int hi = total * (part + 1) / SPLIT;
  __shared__ u32 cnt[512];
  int t = threadIdx.x;
  cnt[t] = 0; cnt[t + 256] = 0;
  __syncthreads();
  const u32* R = srcRec + (size_t)bk * SB_CAP;
  for (int i = lo + t; i < hi; i += 256) atomicAdd(&cnt[R[i] >> 21], 1u);
  __syncthreads();
  int base = bk * 512;
  for (int v = t; v < 512; v += 256) {
    u32 c = cnt[v];
    if (c) atomicAdd(&outdegB[base + v], (int)c);
  }
}

// ---------------- hdetect: heavy-id assignment + dst-bucket scan ----------------
__global__ __launch_bounds__(256) void k_hdetect(const int* __restrict__ outdegB, u32* __restrict__ idAB,
                                                 int* __restrict__ hcA, int* __restrict__ hcB,
                                                 const int* __restrict__ dstCnt, int* __restrict__ bucketBase,
                                                 int* __restrict__ dptr, int nbD, int N) {
  if (blockIdx.x == 0 && threadIdx.x == 0) {
    int s = 0;
    for (int i = 0; i < nbD; ++i) { bucketBase[i] = s; s += min(dstCnt[i], DB_CAP); }
    bucketBase[nbD] = s;
    dptr[N] = s;   // == E (absent overflow)
  }
  int v = blockIdx.x * 256 + threadIdx.x;
  if (v >= N) return;
  int dg = outdegB[v];
  u32 pk = 0;
  if (dg > 50) {
    int idb = atomicAdd(hcB, 1);
    if (idb < HMAX) pk = (u32)(idb + 1);
    if (dg > 100) {
      int ida = atomicAdd(hcA, 1);
      if (ida < HMAX) pk |= (u32)(ida + 1) << 16;
    }
  }
  idAB[v] = pk;
}

// ---------------- hfill: PRNG-bucket heavy edges ----------------
__global__ __launch_bounds__(256) void k_hfill(const int* __restrict__ srcCnt, const u32* __restrict__ srcRec,
                                               const u32* __restrict__ idAB,
                                               int* __restrict__ bcA, u64* __restrict__ bukA,
                                               int* __restrict__ bcB, u64* __restrict__ bukB,
                                               u32 kaA, u32 kbA, u32 kaB, u32 kbB) {
  int bk = blockIdx.x >> 3;
  int part = blockIdx.x & (SPLIT - 1);
  int total = min(srcCnt[bk], SB_CAP);
  int lo = total * part / SPLIT;
  int hi = total * (part + 1) / SPLIT;
  const u32* R = srcRec + (size_t)bk * SB_CAP;
  int base = bk * 512;
  for (int i = lo + threadIdx.x; i < hi; i += 256) {
    u32 r = R[i];
    u32 pk = idAB[base + (int)(r >> 21)];
    if (pk) {
      u32 e = r & 0x1FFFFFu;
      int idb = (int)(pk & 0xFFFFu) - 1;
      if (idb >= 0) {
        u32 w0, w1; tf2x32(kaB, kbB, 0u, e, w0, w1);
        int slot = atomicAdd(&bcB[idb], 1);
        if (slot < MAXD) bukB[(size_t)idb * MAXD + slot] = ((u64)((w0 ^ w1) >> 9) << 32) | e;
      }
      int ida = (int)(pk >> 16) - 1;
      if (ida >= 0) {
        u32 w0, w1; tf2x32(kaA, kbA, 0u, e, w0, w1);
        int slot = atomicAdd(&bcA[ida], 1);
        if (slot < MAXD) bukA[(size_t)ida * MAXD + slot] = ((u64)((w0 ^ w1) >> 9) << 32) | e;
      }
    }
  }
}

// ---------------- rank2: drop rank >= S -> append (eid | bit<<21) to dropList ----------------
__global__ __launch_bounds__(256) void k_rank2(const int* __restrict__ hcA, const int* __restrict__ bcA,
                                               const u64* __restrict__ bukA,
                                               const int* __restrict__ hcB, const int* __restrict__ bcB,
                                               const u64* __restrict__ bukB,
                                               int* __restrict__ dropCnt, u32* __restrict__ dropList) {
  bool isA = blockIdx.x < (HMAX / 4);
  int bx = isA ? blockIdx.x : blockIdx.x - HMAX / 4;
  const int* hcount = isA ? hcA : hcB;
  const int* bcount = isA ? bcA : bcB;
  const u64* bucket = isA ? bukA : bukB;
  int S = isA ? 100 : 50;
  u32 bit = isA ? 1u : 2u;
  int wid = (bx * 256 + (int)threadIdx.x) >> 6;
  int lane = threadIdx.x & 63;
  int hc = hcount[0]; if (hc > HMAX) hc = HMAX;
  if (wid >= hc) return;
  int d = bcount[wid]; if (d > MAXD) d = MAXD;
  const u64* B = bucket + (size_t)wid * MAXD;
  for (int i = lane; i < d; i += 64) {
    u64 ki = B[i];
    int rank = 0;
    for (int j = 0; j < d; ++j) rank += (B[j] < ki) ? 1 : 0;
    if (rank >= S) {
      int idx = atomicAdd(dropCnt, 1);
      if (idx < DROP_CAP) dropList[idx] = ((u32)ki & 0x1FFFFFu) | (bit << 21);
    }
  }
}

// ---------------- phase2: per-bucket counting sort from dstRec -> entries/dptr/dinv ----------------
// dstRec = dstlow7(37:44) | src(21:36) | eid(0:20); dropped edges via LDS hash of dropList
__global__ __launch_bounds__(256) void k_phase2(const int* __restrict__ bucketBase,
                                                const int* __restrict__ dstCnt,
                                                const u64* __restrict__ dstRec,
                                                const int* __restrict__ dropCnt,
                                                const u32* __restrict__ dropList,
                                                u32* __restrict__ entries, int* __restrict__ dptr,
                                                float* __restrict__ dinv1, float* __restrict__ dinv2, int N) {
  int b = blockIdx.x;
  int base = bucketBase[b];
  int cnt0 = min(dstCnt[b], DB_CAP);
  const u64* R = dstRec + (size_t)b * DB_CAP;
  __shared__ u32 cnt[128];
  __shared__ u32 htab[4096];
  __shared__ u32 ws2[2];
  int t = threadIdx.x;
  if (t < 128) cnt[t] = 0;
  for (int i = t; i < 4096; i += 256) htab[i] = 0xFFFFFFFFu;
  __syncthreads();
  int dc = min(dropCnt[0], 3072);
  for (int i = t; i < dc; i += 256) {
    u32 pk = dropList[i];
    u32 key = pk & 0x1FFFFFu;
    u32 h = (key * 2654435761u) >> 20;
    while (true) {
      u32 old = atomicCAS(&htab[h], 0xFFFFFFFFu, pk);
      if (old == 0xFFFFFFFFu) break;
      if ((old & 0x1FFFFFu) == key) { atomicOr(&htab[h], pk & 0x00600000u); break; }
      h = (h + 1) & 4095;
    }
  }
  __syncthreads();
  // pass 1: packed histogram total(0:9) | keep1(10:19) | keep2(20:29)
  for (int i = t; i < cnt0; i += 256) {
    u64 r = R[i];
    u32 dl = (u32)(r >> 37) & 127u;
    u32 key = (u32)r & 0x1FFFFFu;
    u32 drop = 0;
    u32 h = (key * 2654435761u) >> 20;
    while (true) {
      u32 v = htab[h];
      if (v == 0xFFFFFFFFu) break;
      if ((v & 0x1FFFFFu) == key) { drop = (v >> 21) & 3u; break; }
      h = (h + 1) & 4095;
    }
    u32 add = 1u + ((1u - (drop & 1u)) << 10) + ((1u - ((drop >> 1) & 1u)) << 20);
    atomicAdd(&cnt[dl], add);
  }
  __syncthreads();
  u32 c0 = (t < 128) ? cnt[t] : 0;
  u32 tot = c0 & 1023u;
  int lane = t & 63, w = t >> 6;
  u32 incl = tot;
  for (int off = 1; off < 64; off <<= 1) {
    u32 nbv = (u32)__shfl_up((int)incl, off, 64);
    if (lane >= off) incl += nbv;
  }
  if (lane == 63 && w == 0) ws2[0] = incl;
  __syncthreads();
  u32 excl = incl - tot + ((w == 1) ? ws2[0] : 0u);
  int v0 = b * 128 + t;
  if (t < 128 && v0 < N) {
    dptr[v0] = base + (int)excl;
    dinv1[v0] = 1.0f / sqrtf((float)(((c0 >> 10) & 1023u) + 1u));
    dinv2[v0] = 1.0f / sqrtf((float)(((c0 >> 20) & 1023u) + 1u));
  }
  __syncthreads();
  if (t < 128) cnt[t] = excl;
  __syncthreads();
  // pass 2: scatter
  for (int i = t; i < cnt0; i += 256) {
    u64 r = R[i];
    u32 dl = (u32)(r >> 37) & 127u;
    u32 key = (u32)r & 0x1FFFFFu;
    u32 drop = 0;
    u32 h = (key * 2654435761u) >> 20;
    while (true) {
      u32 v = htab[h];
      if (v == 0xFFFFFFFFu) break;
      if ((v & 0x1FFFFFu) == key) { drop = (v >> 21) & 3u; break; }
      h = (h + 1) & 4095;
    }
    u32 src = (u32)(r >> 21) & 0xFFFFu;
    u32 slot = atomicAdd(&cnt[dl], 1u);
    entries[base + slot] = src | ((drop & 1u) ? 0u : (1u << 30)) | ((drop & 2u) ? 0u : (1u << 31));
  }
}

// ---------------- conv1: aggregate h1 + bias + relu + L2 normalize -> bf16 hnb ----------------
// wave per dst; eighth-wave: 8 lanes x uint4(16B) = 128B row, 8 rows in flight + 1-deep pipeline
__global__ __launch_bounds__(256) void k_conv1n(const int* __restrict__ ptr, const u32* __restrict__ entries,
                                                const float* __restrict__ dinv1, const uint4* __restrict__ h1q,
                                                const float* __restrict__ b1, uint4* __restrict__ hnbq, int N) {
  int wid = (blockIdx.x * 256 + threadIdx.x) >> 6;
  if (wid >= N) return;
  int lane = threadIdx.x & 63;
  int lo8 = lane & 7, grp = lane >> 3;
  int beg = ptr[wid], end = ptr[wid + 1];
  float a0 = 0.f, a1 = 0.f, a2 = 0.f, a3 = 0.f, a4 = 0.f, a5 = 0.f, a6 = 0.f, a7 = 0.f;
  for (int cb = beg; cb < end; cb += 64) {
    int idx = cb + lane;
    float wgt = 0.f; int s = 0;
    if (idx < end) {
      u32 e = entries[idx];
      s = (int)(e & 0xFFFFu);
      if (e & (1u << 30)) wgt = dinv1[s];
    }
    int nq = (min(64, end - cb) + 7) >> 3;
    int j = grp;
    float w = __shfl(wgt, j, 64);
    int sj = __shfl(s, j, 64);
    uint4 uv = h1q[(size_t)sj * 8 + lo8];
    for (int i = 1; i < nq; ++i) {
      int j2 = j + 8;
      float w2 = __shfl(wgt, j2, 64);
      int s2 = __shfl(s, j2, 64);
      uint4 uv2 = h1q[(size_t)s2 * 8 + lo8];
      a0 = fmaf(w, bflo(uv.x), a0); a1 = fmaf(w, bfhi(uv.x), a1);
      a2 = fmaf(w, bflo(uv.y), a2); a3 = fmaf(w, bfhi(uv.y), a3);
      a4 = fmaf(w, bflo(uv.z), a4); a5 = fmaf(w, bfhi(uv.z), a5);
      a6 = fmaf(w, bflo(uv.w), a6); a7 = fmaf(w, bfhi(uv.w), a7);
      w = w2; uv = uv2; j = j2;
    }
    a0 = fmaf(w, bflo(uv.x), a0); a1 = fmaf(w, bfhi(uv.x), a1);
    a2 = fmaf(w, bflo(uv.y), a2); a3 = fmaf(w, bfhi(uv.y), a3);
    a4 = fmaf(w, bflo(uv.z), a4); a5 = fmaf(w, bfhi(uv.z), a5);
    a6 = fmaf(w, bflo(uv.w), a6); a7 = fmaf(w, bfhi(uv.w), a7);
  }
#pragma unroll
  for (int off = 8; off < 64; off <<= 1) {
    a0 += __shfl_xor(a0, off, 64); a1 += __shfl_xor(a1, off, 64);
    a2 += __shfl_xor(a2, off, 64); a3 += __shfl_xor(a3, off, 64);
    a4 += __shfl_xor(a4, off, 64); a5 += __shfl_xor(a5, off, 64);
    a6 += __shfl_xor(a6, off, 64); a7 += __shfl_xor(a7, off, 64);
  }
  float dv = dinv1[wid];
  uint4 uo = h1q[(size_t)wid * 8 + lo8];
  a0 = fmaf(dv, bflo(uo.x), a0); a1 = fmaf(dv, bfhi(uo.x), a1);
  a2 = fmaf(dv, bflo(uo.y), a2); a3 = fmaf(dv, bfhi(uo.y), a3);
  a4 = fmaf(dv, bflo(uo.z), a4); a5 = fmaf(dv, bfhi(uo.z), a5);
  a6 = fmaf(dv, bflo(uo.w), a6); a7 = fmaf(dv, bfhi(uo.w), a7);
  float4 bbA = ((const float4*)b1)[lo8 * 2];
  float4 bbB = ((const float4*)b1)[lo8 * 2 + 1];
  float o0 = fmaxf(fmaf(dv, a0, bbA.x), 0.f);
  float o1 = fmaxf(fmaf(dv, a1, bbA.y), 0.f);
  float o2 = fmaxf(fmaf(dv, a2, bbA.z), 0.f);
  float o3 = fmaxf(fmaf(dv, a3, bbA.w), 0.f);
  float o4 = fmaxf(fmaf(dv, a4, bbB.x), 0.f);
  float o5 = fmaxf(fmaf(dv, a5, bbB.y), 0.f);
  float o6 = fmaxf(fmaf(dv, a6, bbB.z), 0.f);
  float o7 = fmaxf(fmaf(dv, a7, bbB.w), 0.f);
  float ss = fmaf(o0, o0, fmaf(o1, o1, fmaf(o2, o2, o3 * o3)))
           + fmaf(o4, o4, fmaf(o5, o5, fmaf(o6, o6, o7 * o7)));
#pragma unroll
  for (int off = 1; off < 8; off <<= 1) ss += __shfl_xor(ss, off, 8);
  float sc = 1.f / fmaxf(sqrtf(ss), 1e-12f);
  if (lane < 8) {
    uint4 pv;
    pv.x = (u32)f2bf(o0 * sc) | ((u32)f2bf(o1 * sc) << 16);
    pv.y = (u32)f2bf(o2 * sc) | ((u32)f2bf(o3 * sc) << 16);
    pv.z = (u32)f2bf(o4 * sc) | ((u32)f2bf(o5 * sc) << 16);
    pv.w = (u32)f2bf(o6 * sc) | ((u32)f2bf(o7 * sc) << 16);
    hnbq[(size_t)wid * 8 + lo8] = pv;
  }
}

// ---------------- agg2: aggregate hnb with dinv2 -> bf16 agg2b ----------------
__global__ __launch_bounds__(256) void k_agg2(const int* __restrict__ ptr, const u32* __restrict__ entries,
                                              const float* __restrict__ dinv2, const uint4* __restrict__ hnq,
                                              uint4* __restrict__ agg2q, int N) {
  int wid = (blockIdx.x * 256 + threadIdx.x) >> 6;
  if (wid >= N) return;
  int lane = threadIdx.x & 63;
  int lo8 = lane & 7, grp = lane >> 3;
  int beg = ptr[wid], end = ptr[wid + 1];
  float a0 = 0.f, a1 = 0.f, a2 = 0.f, a3 = 0.f, a4 = 0.f, a5 = 0.f, a6 = 0.f, a7 = 0.f;
  for (int cb = beg; cb < end; cb += 64) {
    int idx = cb + lane;
    float wgt = 0.f; int s = 0;
    if (idx < end) {
      u32 e = entries[idx];
      s = (int)(e & 0xFFFFu);
      if (e & (1u << 31)) wgt = dinv2[s];
    }
    int nq = (min(64, end - cb) + 7) >> 3;
    int j = grp;
    float w = __shfl(wgt, j, 64);
    int sj = __shfl(s, j, 64);
    uint4 uv = hnq[(size_t)sj * 8 + lo8];
    for (int i = 1; i < nq; ++i) {
      int j2 = j + 8;
      float w2 = __shfl(wgt, j2, 64);
      int s2 = __shfl(s, j2, 64);
      uint4 uv2 = hnq[(size_t)s2 * 8 + lo8];
      a0 = fmaf(w, bflo(uv.x), a0); a1 = fmaf(w, bfhi(uv.x), a1);
      a2 = fmaf(w, bflo(uv.y), a2); a3 = fmaf(w, bfhi(uv.y), a3);
      a4 = fmaf(w, bflo(uv.z), a4); a5 = fmaf(w, bfhi(uv.z), a5);
      a6 = fmaf(w, bflo(uv.w), a6); a7 = fmaf(w, bfhi(uv.w), a7);
      w = w2; uv = uv2; j = j2;
    }
    a0 = fmaf(w, bflo(uv.x), a0); a1 = fmaf(w, bfhi(uv.x), a1);
    a2 = fmaf(w, bflo(uv.y), a2); a3 = fmaf(w, bfhi(uv.y), a3);
    a4 = fmaf(w, bflo(uv.z), a4); a5 = fmaf(w, bfhi(uv.z), a5);
    a6 = fmaf(w, bflo(uv.w), a6); a7 = fmaf(w, bfhi(uv.w), a7);
  }
#pragma unroll
  for (int off = 8; off < 64; off <<= 1) {
    a0 += __shfl_xor(a0, off, 64); a1 += __shfl_xor(a1, off, 64);
    a2 += __shfl_xor(a2, off, 64); a3 += __shfl_xor(a3, off, 64);
    a4 += __shfl_xor(a4, off, 64); a5 += __shfl_xor(a5, off, 64);
    a6 += __shfl_xor(a6, off, 64); a7 += __shfl_xor(a7, off, 64);
  }
  float dv = dinv2[wid];
  uint4 uo = hnq[(size_t)wid * 8 + lo8];
  a0 = fmaf(dv, bflo(uo.x), a0); a1 = fmaf(dv, bfhi(uo.x), a1);
  a2 = fmaf(dv, bflo(uo.y), a2); a3 = fmaf(dv, bfhi(uo.y), a3);
  a4 = fmaf(dv, bflo(uo.z), a4); a5 = fmaf(dv, bfhi(uo.z), a5);
  a6 = fmaf(dv, bflo(uo.w), a6); a7 = fmaf(dv, bfhi(uo.w), a7);
  if (lane < 8) {
    uint4 pv;
    pv.x = (u32)f2bf(dv * a0) | ((u32)f2bf(dv * a1) << 16);
    pv.y = (u32)f2bf(dv * a2) | ((u32)f2bf(dv * a3) << 16);
    pv.z = (u32)f2bf(dv * a4) | ((u32)f2bf(dv * a5) << 16);
    pv.w = (u32)f2bf(dv * a6) | ((u32)f2bf(dv * a7) << 16);
    agg2q[(size_t)wid * 8 + lo8] = pv;
  }
}

// ---------------- gemm2f: out = agg2b @ W2 + b2 (MFMA, fused bias, fp32 out) ----------------
#define G2S 72
__global__ __launch_bounds__(256) void k_gemm2f(const u16* __restrict__ aggb, const u16* __restrict__ W2t,
                                                const float* __restrict__ b2, float* __restrict__ out, int N) {
  __shared__ u16 hs[64 * G2S];
  __shared__ u16 ws[128 * G2S];
  int t = threadIdx.x;
  int wv = t >> 6, lane = t & 63;
  int qd = lane >> 4, md = lane & 15;
  int m0 = blockIdx.x * 64;
#pragma unroll
  for (int i = 0; i < 2; ++i) {                 // stage aggb: 64 rows x 64 u16 = 512 uint4
    int cc = t + 256 * i;
    int r = cc >> 3, kc = (cc & 7) * 8;
    int grow = m0 + r; if (grow >= N) grow = N - 1;
    *((uint4*)(hs + r * G2S + kc)) = *((const uint4*)(aggb + (size_t)grow * 64 + kc));
  }
#pragma unroll
  for (int i = 0; i < 4; ++i) {                 // stage W2t (128x64 u16)
    int cc = t + 256 * i;
    int n = cc >> 3, kc = (cc & 7) * 8;
    *((uint4*)(ws + n * G2S + kc)) = *((const uint4*)(W2t + n * 64 + kc));
  }
  __syncthreads();
  f4 acc[8] = {};
#pragma unroll
  for (int kk = 0; kk < 64; kk += 32) {
    bh8 af = *((const bh8*)(hs + (16 * wv + md) * G2S + kk + qd * 8));
#pragma unroll
    for (int nt = 0; nt < 8; ++nt) {
      bh8 bf = *((const bh8*)(ws + (nt * 16 + md) * G2S + kk + qd * 8));
      acc[nt] = mfma16(af, bf, acc[nt]);
    }
  }
#pragma unroll
  for (int nt = 0; nt < 8; ++nt) {
    float bv = b2[nt * 16 + md];
#pragma unroll
    for (int r = 0; r < 4; ++r) {
      int row = m0 + 16 * wv + qd * 4 + r;
      if (row < N) out[(size_t)row * 128 + nt * 16 + md] = acc[nt][r] + bv;
    }
  }
}

// ---------------- launch ----------------
extern "C" void kernel_launch(void* const* d_in, const int* in_sizes, int n_in,
                              void* d_out, int out_size, void* d_ws, size_t ws_size,
                              hipStream_t stream) {
  const float* x  = (const float*)d_in[0];
  const int*   ei = (const int*)d_in[1];
  const float* W1 = (const float*)d_in[2];
  const float* b1 = (const float*)d_in[3];
  const float* W2 = (const float*)d_in[4];
  const float* b2 = (const float*)d_in[5];
  const int N = in_sizes[0] / 256;
  const int E = in_sizes[1] / 2;
  const int nbS = (N + 511) >> 9;   // src buckets (98; <=128)
  const int nbD = (N + 127) >> 7;   // dst buckets (391; <=512)

  u32 sk1a, sk1b, sk2a, sk2b;
  tf2x32(0u, 42u, 0u, 0u, sk1a, sk1b);
  tf2x32(0u, 42u, 0u, 1u, sk2a, sk2b);

  char* p = (char*)d_ws;
  auto alloc = [&](size_t bytes) { char* r = p; p += (bytes + 255) & ~(size_t)255; return r; };
  // --- zero-init group (contiguous) ---
  int* dstCnt      = (int*)alloc(512 * 4);
  int* srcCnt      = (int*)alloc(128 * 4);
  int* hcbA        = (int*)alloc((size_t)(1 + HMAX) * 4);
  int* hcbB        = (int*)alloc((size_t)(1 + HMAX) * 4);
  int* outdegB     = (int*)alloc((size_t)nbS * 512 * 4);
  int* dropCnt     = (int*)alloc(256);
  char* zero_end = p;
  // --- rest ---
  u32* dropList = (u32*)alloc((size_t)DROP_CAP * 4);
  u32* idAB     = (u32*)alloc((size_t)nbS * 512 * 4);
  u16* h1b      = (u16*)alloc((size_t)N * 64 * 2);
  u16* hnb      = (u16*)alloc((size_t)N * 64 * 2);
  u16* agg2b    = (u16*)alloc((size_t)N * 64 * 2);
  float* dinv1  = (float*)alloc((size_t)N * 4);
  float* dinv2  = (float*)alloc((size_t)N * 4);
  int* dptr     = (int*)alloc((size_t)(N + 1) * 4);
  int* bucketBase = (int*)alloc(513 * 4);
  u32* entries  = (u32*)alloc((size_t)E * 4);
  u32* srcRec   = (u32*)alloc((size_t)nbS * SB_CAP * 4);
  u64* dstRec   = (u64*)alloc((size_t)nbD * DB_CAP * 8);
  u64* bukA     = (u64*)alloc((size_t)HMAX * MAXD * 8);
  u64* bukB     = (u64*)alloc((size_t)HMAX * MAXD * 8);
  u16* W2t      = (u16*)alloc(64 * 128 * 2);

  int* hcA = hcbA; int* bcA = hcbA + 1;
  int* hcB = hcbB; int* bcB = hcbB + 1;

  hipMemsetAsync(dstCnt, 0x00, (size_t)(zero_end - (char*)dstCnt), stream);

  const int nBin = (E + SBCHUNK - 1) / SBCHUNK;
  const int nGemm = (N + 63) / 64;
  k_mega1<<<nBin + nGemm + 1, 256, 0, stream>>>(ei, E, x, N, W1, W2,
                                                srcCnt, srcRec, dstCnt, dstRec, h1b, W2t, nBin);
  k_shist<<<nbS * SPLIT, 256, 0, stream>>>(srcCnt, srcRec, outdegB);
  k_hdetect<<<(N + 255) / 256, 256, 0, stream>>>(outdegB, idAB, hcA, hcB, dstCnt, bucketBase,
                                                 dptr, nbD, N);
  k_hfill<<<nbS * SPLIT, 256, 0, stream>>>(srcCnt, srcRec, idAB, bcA, bukA, bcB, bukB,
                                           sk1a, sk1b, sk2a, sk2b);
  k_rank2<<<HMAX / 2, 256, 0, stream>>>(hcA, bcA, bukA, hcB, bcB, bukB, dropCnt, dropList);
  k_phase2<<<nbD, 256, 0, stream>>>(bucketBase, dstCnt, dstRec, dropCnt, dropList,
                                    entries, dptr, dinv1, dinv2, N);
  k_conv1n<<<(N * 64 + 255) / 256, 256, 0, stream>>>(dptr, entries, dinv1, (const uint4*)h1b, b1,
                                                     (uint4*)hnb, N);
  k_agg2<<<(N * 64 + 255) / 256, 256, 0, stream>>>(dptr, entries, dinv2, (const uint4*)hnb,
                                                   (uint4*)agg2b, N);
  k_gemm2f<<<(N + 63) / 64, 256, 0, stream>>>(agg2b, W2t, b2, (float*)d_out, N);
}